// Round 5
// baseline (4054.919 us; speedup 1.0000x reference)
//
#include <hip/hip_runtime.h>

#define HIDDEN 4096
#define INTER 14336
#define NTOK 8192   // B*S = 4*2048

typedef _Float16 half8 __attribute__((ext_vector_type(8)));
typedef float floatx4 __attribute__((ext_vector_type(4)));

#define AS1C(p) ((const __attribute__((address_space(1))) void*)(p))
#define AS3(p)  ((__attribute__((address_space(3))) void*)(p))
#define SBAR()  __builtin_amdgcn_s_barrier()
#define WAIT_VM0() asm volatile("s_waitcnt vmcnt(0)" ::: "memory")
#define PRIO(x) __builtin_amdgcn_s_setprio(x)
#define MFMA16(A,B,C) __builtin_amdgcn_mfma_f32_16x16x32_f16(A,B,C,0,0,0)

// ---------------- conversion kernels ----------------

__global__ void cvt_w_kernel(const int* __restrict__ src, _Float16* __restrict__ dst, long n) {
    long i0 = ((long)blockIdx.x * blockDim.x + threadIdx.x) * 8;
    long stride = (long)gridDim.x * blockDim.x * 8;
    for (long i = i0; i < n; i += stride) {
        int4 a = *(const int4*)(src + i);
        int4 b = *(const int4*)(src + i + 4);
        half8 h;
        h[0] = (_Float16)a.x; h[1] = (_Float16)a.y; h[2] = (_Float16)a.z; h[3] = (_Float16)a.w;
        h[4] = (_Float16)b.x; h[5] = (_Float16)b.y; h[6] = (_Float16)b.z; h[7] = (_Float16)b.w;
        *(half8*)(dst + i) = h;
    }
}

__global__ void cvt_x_kernel(const float* __restrict__ src, _Float16* __restrict__ dst, long n) {
    long i0 = ((long)blockIdx.x * blockDim.x + threadIdx.x) * 8;
    long stride = (long)gridDim.x * blockDim.x * 8;
    for (long i = i0; i < n; i += stride) {
        float4 a = *(const float4*)(src + i);
        float4 b = *(const float4*)(src + i + 4);
        half8 h;
        h[0] = (_Float16)a.x; h[1] = (_Float16)a.y; h[2] = (_Float16)a.z; h[3] = (_Float16)a.w;
        h[4] = (_Float16)b.x; h[5] = (_Float16)b.y; h[6] = (_Float16)b.z; h[7] = (_Float16)b.w;
        *(half8*)(dst + i) = h;
    }
}

// ---------------- fused gate+up (4-phase, stage-all-at-P0) ----------------
// C[m,n] = sum_k X[m,k]*W[n,k]. BM=256, BN=128, BK=64, 512 thr (8 waves, 2M x 4N).
// LDS 128KB: 2buf x (A 32KB + Bg 16KB + Bu 16KB).
// Phases: P0 g(m0-3) [ds A0-3+G, issue ALL t+1 staging], P1 g(m4-7) [ds A4-7],
//         P2 u(m0-3) [ds U], P3 u(m4-7) [vmcnt(0): loads are ~3 phases old].
// Grid: XCD x owns bn in [14x,14x+14), bm fast -> weights fetched from HBM once,
// X LLC-resident.

__global__ __launch_bounds__(512, 2) void gateup_kernel(
        const _Float16* __restrict__ Aptr, const _Float16* __restrict__ Bgp,
        const _Float16* __restrict__ Bup, const float* __restrict__ gsc,
        const float* __restrict__ usc, _Float16* __restrict__ H)
{
    constexpr int KDIM = HIDDEN;
    constexpr int NT = KDIM / 64;      // 64
    __shared__ _Float16 sA[2][256 * 64];
    __shared__ _Float16 sG[2][128 * 64];
    __shared__ _Float16 sU[2][128 * 64];

    const int tid  = threadIdx.x;
    const int lane = tid & 63;
    const int wid  = tid >> 6;
    const int wr   = wid >> 2;   // 0..1
    const int wc   = wid & 3;    // 0..3

    // column-major XCD chunks: xcd owns 14 bn columns, bm fast
    const int bid  = blockIdx.x;
    const int xcd  = bid & 7;
    const int loc  = bid >> 3;          // 0..447
    const int bm   = loc & 31;          // fast axis (32 M-tiles)
    const int bn   = xcd * 14 + (loc >> 5);

    // staging addresses (T2: pre-swizzled global source slot)
    const int srow  = tid >> 3;                  // 0..63
    const int sslot = (tid & 7) ^ (srow & 7);
    const _Float16* gA = Aptr + ((long)bm * 256 + srow) * KDIM + sslot * 8;
    const _Float16* gG = Bgp + ((long)bn * 128 + srow) * KDIM + sslot * 8;
    const _Float16* gU = Bup + ((long)bn * 128 + srow) * KDIM + sslot * 8;

    auto stageAll = [&](int t) {   // full t-tile -> buf[t&1]: 8 loads/thread
        const int b = t & 1;
        _Float16* dA = &sA[b][tid * 8];
        _Float16* dG = &sG[b][tid * 8];
        _Float16* dU = &sU[b][tid * 8];
        const _Float16* sa = gA + (long)t * 64;
        const _Float16* sg = gG + (long)t * 64;
        const _Float16* su = gU + (long)t * 64;
#pragma unroll
        for (int p = 0; p < 4; ++p)
            __builtin_amdgcn_global_load_lds(AS1C(sa + (long)p * 64 * KDIM), AS3(dA + p * 4096), 16, 0, 0);
#pragma unroll
        for (int p = 0; p < 2; ++p) {
            __builtin_amdgcn_global_load_lds(AS1C(sg + (long)p * 64 * KDIM), AS3(dG + p * 4096), 16, 0, 0);
            __builtin_amdgcn_global_load_lds(AS1C(su + (long)p * 64 * KDIM), AS3(dU + p * 4096), 16, 0, 0);
        }
    };

    // ds_read fragment offsets (elements); row&7 == lane&7 for all frags
    const int arow = wr * 128 + (lane & 15);
    const int brow = wc * 32  + (lane & 15);
    const int sl0 = ((lane >> 4) ^ (lane & 7)) * 8;
    const int sl1 = ((4 + (lane >> 4)) ^ (lane & 7)) * 8;
    const int aof0 = arow * 64 + sl0, aof1 = arow * 64 + sl1;
    const int bof0 = brow * 64 + sl0, bof1 = brow * 64 + sl1;

    floatx4 ag[8][2] = {};
    floatx4 au[8][2] = {};
    half8 a[8][2], bg[2][2], bu[2][2];

    stageAll(0);
    WAIT_VM0();
    SBAR();

    for (int t = 0; t < NT; ++t) {
        const _Float16* A = &sA[t & 1][0];
        const _Float16* G = &sG[t & 1][0];
        const _Float16* U = &sU[t & 1][0];

        // ---- P0: issue ALL t+1 staging; ds A0-3 + G; MFMA g m0-3 ----
        if (t + 1 < NT) stageAll(t + 1);
#pragma unroll
        for (int m = 0; m < 4; ++m) {
            a[m][0] = *(const half8*)(A + aof0 + m * 1024);
            a[m][1] = *(const half8*)(A + aof1 + m * 1024);
        }
#pragma unroll
        for (int n = 0; n < 2; ++n) {
            bg[n][0] = *(const half8*)(G + bof0 + n * 1024);
            bg[n][1] = *(const half8*)(G + bof1 + n * 1024);
        }
        SBAR();
        PRIO(1);
#pragma unroll
        for (int m = 0; m < 4; ++m)
#pragma unroll
            for (int n = 0; n < 2; ++n) {
                ag[m][n] = MFMA16(a[m][0], bg[n][0], ag[m][n]);
                ag[m][n] = MFMA16(a[m][1], bg[n][1], ag[m][n]);
            }
        PRIO(0);
        SBAR();

        // ---- P1: ds A4-7; MFMA g m4-7 ----
#pragma unroll
        for (int m = 4; m < 8; ++m) {
            a[m][0] = *(const half8*)(A + aof0 + m * 1024);
            a[m][1] = *(const half8*)(A + aof1 + m * 1024);
        }
        SBAR();
        PRIO(1);
#pragma unroll
        for (int m = 4; m < 8; ++m)
#pragma unroll
            for (int n = 0; n < 2; ++n) {
                ag[m][n] = MFMA16(a[m][0], bg[n][0], ag[m][n]);
                ag[m][n] = MFMA16(a[m][1], bg[n][1], ag[m][n]);
            }
        PRIO(0);
        SBAR();

        // ---- P2: ds U; MFMA u m0-3 ----
#pragma unroll
        for (int n = 0; n < 2; ++n) {
            bu[n][0] = *(const half8*)(U + bof0 + n * 1024);
            bu[n][1] = *(const half8*)(U + bof1 + n * 1024);
        }
        SBAR();
        PRIO(1);
#pragma unroll
        for (int m = 0; m < 4; ++m)
#pragma unroll
            for (int n = 0; n < 2; ++n) {
                au[m][n] = MFMA16(a[m][0], bu[n][0], au[m][n]);
                au[m][n] = MFMA16(a[m][1], bu[n][1], au[m][n]);
            }
        PRIO(0);
        SBAR();

        // ---- P3: MFMA u m4-7; tile boundary (loads ~3 phases old) ----
        PRIO(1);
#pragma unroll
        for (int m = 4; m < 8; ++m)
#pragma unroll
            for (int n = 0; n < 2; ++n) {
                au[m][n] = MFMA16(a[m][0], bu[n][0], au[m][n]);
                au[m][n] = MFMA16(a[m][1], bu[n][1], au[m][n]);
            }
        PRIO(0);
        WAIT_VM0();
        SBAR();
    }

    // ---- epilogue: h = silu(g*gs) * (u*us), fp16 ----
    const int orow = bm * 256 + wr * 128 + ((lane >> 4) * 4);
    const int ocol = bn * 128 + wc * 32 + (lane & 15);
#pragma unroll
    for (int n = 0; n < 2; ++n) {
        const int col = ocol + n * 16;
        const float gs = gsc[col];
        const float us = usc[col];
#pragma unroll
        for (int m = 0; m < 8; ++m) {
            const int row = orow + m * 16;
#pragma unroll
            for (int q = 0; q < 4; ++q) {
                const float g = ag[m][n][q] * gs;
                const float u = au[m][n][q] * us;
                H[(long)(row + q) * INTER + col] = (_Float16)(g / (1.0f + __expf(-g)) * u);
            }
        }
    }
}

// ---------------- down GEMM (4-phase 256x256, stage-all-at-P0) ----------------

__global__ __launch_bounds__(512, 2) void down_kernel(
        const _Float16* __restrict__ Aptr, const _Float16* __restrict__ Bptr,
        const float* __restrict__ dsc, float* __restrict__ out)
{
    constexpr int KDIM = INTER;
    constexpr int NT = KDIM / 64;     // 224
    constexpr int NBN = HIDDEN / 256; // 16
    __shared__ _Float16 sA[2][256 * 64];
    __shared__ _Float16 sB[2][256 * 64];

    const int tid  = threadIdx.x;
    const int lane = tid & 63;
    const int wid  = tid >> 6;
    const int wr   = wid >> 2;
    const int wc   = wid & 3;

    // row-major XCD chunks (bn fast): Wd LLC-resident, H panels fetched once
    const int nwg = gridDim.x;
    const int bid = blockIdx.x;
    const int swz = (bid & 7) * (nwg >> 3) + (bid >> 3);
    const int bm = swz / NBN;
    const int bn = swz % NBN;

    const int srow  = tid >> 3;
    const int sslot = (tid & 7) ^ (srow & 7);
    const _Float16* gA = Aptr + ((long)bm * 256 + srow) * KDIM + sslot * 8;
    const _Float16* gB = Bptr + ((long)bn * 256 + srow) * KDIM + sslot * 8;

    auto stageAll = [&](int t) {   // 8 loads/thread
        const int b = t & 1;
        _Float16* dA = &sA[b][tid * 8];
        _Float16* dB = &sB[b][tid * 8];
        const _Float16* sa = gA + (long)t * 64;
        const _Float16* sb = gB + (long)t * 64;
#pragma unroll
        for (int p = 0; p < 4; ++p) {
            __builtin_amdgcn_global_load_lds(AS1C(sa + (long)p * 64 * KDIM), AS3(dA + p * 4096), 16, 0, 0);
            __builtin_amdgcn_global_load_lds(AS1C(sb + (long)p * 64 * KDIM), AS3(dB + p * 4096), 16, 0, 0);
        }
    };

    const int arow = wr * 128 + (lane & 15);
    const int brow = wc * 64  + (lane & 15);
    const int sl0 = ((lane >> 4) ^ (lane & 7)) * 8;
    const int sl1 = ((4 + (lane >> 4)) ^ (lane & 7)) * 8;
    const int aof0 = arow * 64 + sl0, aof1 = arow * 64 + sl1;
    const int bof0 = brow * 64 + sl0, bof1 = brow * 64 + sl1;

    floatx4 acc[8][4] = {};
    half8 a[8][2], b[4][2];

    stageAll(0);
    WAIT_VM0();
    SBAR();

    for (int t = 0; t < NT; ++t) {
        const _Float16* A = &sA[t & 1][0];
        const _Float16* B = &sB[t & 1][0];

        // ---- P0: issue ALL t+1 staging; ds A0-3 + B0-1; MFMA m0-3 x n0-1 ----
        if (t + 1 < NT) stageAll(t + 1);
#pragma unroll
        for (int m = 0; m < 4; ++m) {
            a[m][0] = *(const half8*)(A + aof0 + m * 1024);
            a[m][1] = *(const half8*)(A + aof1 + m * 1024);
        }
#pragma unroll
        for (int n = 0; n < 2; ++n) {
            b[n][0] = *(const half8*)(B + bof0 + n * 1024);
            b[n][1] = *(const half8*)(B + bof1 + n * 1024);
        }
        SBAR();
        PRIO(1);
#pragma unroll
        for (int m = 0; m < 4; ++m)
#pragma unroll
            for (int n = 0; n < 2; ++n) {
                acc[m][n] = MFMA16(a[m][0], b[n][0], acc[m][n]);
                acc[m][n] = MFMA16(a[m][1], b[n][1], acc[m][n]);
            }
        PRIO(0);
        SBAR();

        // ---- P1: ds B2-3; MFMA m0-3 x n2-3 ----
#pragma unroll
        for (int n = 2; n < 4; ++n) {
            b[n][0] = *(const half8*)(B + bof0 + n * 1024);
            b[n][1] = *(const half8*)(B + bof1 + n * 1024);
        }
        SBAR();
        PRIO(1);
#pragma unroll
        for (int m = 0; m < 4; ++m)
#pragma unroll
            for (int n = 2; n < 4; ++n) {
                acc[m][n] = MFMA16(a[m][0], b[n][0], acc[m][n]);
                acc[m][n] = MFMA16(a[m][1], b[n][1], acc[m][n]);
            }
        PRIO(0);
        SBAR();

        // ---- P2: ds A4-7; MFMA m4-7 x n2-3 ----
#pragma unroll
        for (int m = 4; m < 8; ++m) {
            a[m][0] = *(const half8*)(A + aof0 + m * 1024);
            a[m][1] = *(const half8*)(A + aof1 + m * 1024);
        }
        SBAR();
        PRIO(1);
#pragma unroll
        for (int m = 4; m < 8; ++m)
#pragma unroll
            for (int n = 2; n < 4; ++n) {
                acc[m][n] = MFMA16(a[m][0], b[n][0], acc[m][n]);
                acc[m][n] = MFMA16(a[m][1], b[n][1], acc[m][n]);
            }
        PRIO(0);
        SBAR();

        // ---- P3: MFMA m4-7 x n0-1; boundary ----
        PRIO(1);
#pragma unroll
        for (int m = 4; m < 8; ++m)
#pragma unroll
            for (int n = 0; n < 2; ++n) {
                acc[m][n] = MFMA16(a[m][0], b[n][0], acc[m][n]);
                acc[m][n] = MFMA16(a[m][1], b[n][1], acc[m][n]);
            }
        PRIO(0);
        WAIT_VM0();
        SBAR();
    }

    const int orow = bm * 256 + wr * 128 + ((lane >> 4) * 4);
    const int ocol = bn * 256 + wc * 64 + (lane & 15);
#pragma unroll
    for (int n = 0; n < 4; ++n) {
        const int col = ocol + n * 16;
        const float sc = dsc[col];
#pragma unroll
        for (int m = 0; m < 8; ++m) {
            const int row = orow + m * 16;
#pragma unroll
            for (int q = 0; q < 4; ++q)
                out[(long)(row + q) * HIDDEN + col] = acc[m][n][q] * sc;
        }
    }
}

// ---------------- launch ----------------

extern "C" void kernel_launch(void* const* d_in, const int* in_sizes, int n_in,
                              void* d_out, int out_size, void* d_ws, size_t ws_size,
                              hipStream_t stream) {
    const float* x   = (const float*)d_in[0];
    const int*   gw  = (const int*)d_in[1];
    const float* gsc = (const float*)d_in[2];
    const int*   uw  = (const int*)d_in[3];
    const float* usc = (const float*)d_in[4];
    const int*   dw  = (const int*)d_in[5];
    const float* dsc = (const float*)d_in[6];
    float* out = (float*)d_out;

    char* ws = (char*)d_ws;
    _Float16* x16  = (_Float16*)(ws);                    //  64 MiB
    _Float16* wg16 = (_Float16*)(ws + 67108864ll);       // 112 MiB
    _Float16* wu16 = (_Float16*)(ws + 184549376ll);      // 112 MiB
    _Float16* wd16 = (_Float16*)(ws + 301989888ll);      // 112 MiB
    _Float16* h16  = (_Float16*)(ws + 419430400ll);      // 224 MiB

    cvt_x_kernel<<<4096, 256, 0, stream>>>(x,  x16,  (long)NTOK * HIDDEN);
    cvt_w_kernel<<<4096, 256, 0, stream>>>(gw, wg16, (long)INTER * HIDDEN);
    cvt_w_kernel<<<4096, 256, 0, stream>>>(uw, wu16, (long)INTER * HIDDEN);
    cvt_w_kernel<<<4096, 256, 0, stream>>>(dw, wd16, (long)HIDDEN * INTER);

    // fused gate+up+SwiGLU: [8192 x 14336], h fp16
    gateup_kernel<<<(NTOK / 256) * (INTER / 128), 512, 0, stream>>>(
        x16, wg16, wu16, gsc, usc, h16);
    // down: [8192 x 4096] = H * Wd^T, fp32 out
    down_kernel<<<(NTOK / 256) * (HIDDEN / 256), 512, 0, stream>>>(
        h16, wd16, dsc, out);
}

// Round 6
// 3376.865 us; speedup vs baseline: 1.2008x; 1.2008x over previous
//
#include <hip/hip_runtime.h>

#define HIDDEN 4096
#define INTER 14336
#define NTOK 8192   // B*S = 4*2048

typedef _Float16 half8 __attribute__((ext_vector_type(8)));
typedef float floatx4 __attribute__((ext_vector_type(4)));

#define AS1C(p) ((const __attribute__((address_space(1))) void*)(p))
#define AS3(p)  ((__attribute__((address_space(3))) void*)(p))
#define SBAR()  __builtin_amdgcn_s_barrier()
#define WAIT_VM0() asm volatile("s_waitcnt vmcnt(0)" ::: "memory")
#define WAIT_VM8() asm volatile("s_waitcnt vmcnt(8)" ::: "memory")
#define PRIO(x) __builtin_amdgcn_s_setprio(x)
#define MFMA16(A,B,C) __builtin_amdgcn_mfma_f32_16x16x32_f16(A,B,C,0,0,0)

// ---------------- conversion kernels ----------------

__global__ void cvt_w_kernel(const int* __restrict__ src, _Float16* __restrict__ dst, long n) {
    long i0 = ((long)blockIdx.x * blockDim.x + threadIdx.x) * 8;
    long stride = (long)gridDim.x * blockDim.x * 8;
    for (long i = i0; i < n; i += stride) {
        int4 a = *(const int4*)(src + i);
        int4 b = *(const int4*)(src + i + 4);
        half8 h;
        h[0] = (_Float16)a.x; h[1] = (_Float16)a.y; h[2] = (_Float16)a.z; h[3] = (_Float16)a.w;
        h[4] = (_Float16)b.x; h[5] = (_Float16)b.y; h[6] = (_Float16)b.z; h[7] = (_Float16)b.w;
        *(half8*)(dst + i) = h;
    }
}

__global__ void cvt_x_kernel(const float* __restrict__ src, _Float16* __restrict__ dst, long n) {
    long i0 = ((long)blockIdx.x * blockDim.x + threadIdx.x) * 8;
    long stride = (long)gridDim.x * blockDim.x * 8;
    for (long i = i0; i < n; i += stride) {
        float4 a = *(const float4*)(src + i);
        float4 b = *(const float4*)(src + i + 4);
        half8 h;
        h[0] = (_Float16)a.x; h[1] = (_Float16)a.y; h[2] = (_Float16)a.z; h[3] = (_Float16)a.w;
        h[4] = (_Float16)b.x; h[5] = (_Float16)b.y; h[6] = (_Float16)b.z; h[7] = (_Float16)b.w;
        *(half8*)(dst + i) = h;
    }
}

// ---------------- fused gate+up (4-phase, depth-2 prefetch) ----------------
// C[m,n] = sum_k X[m,k]*W[n,k]. BM=256, BN=128, BK=64, 512 thr (8 waves, 2M x 4N).
// LDS 128KB: 2buf x (A 32KB + Bg 16KB + Bu 16KB).
// Phases: P0 g(m0-3) [ds A0-3+G], P1 g(m4-7) [ds A4-7], P2 u(m0-3) [ds U],
//         P3 u(m4-7) [issue ALL t+2 staging at P3-start (cur buf fully read by
//         end-P2); end: vmcnt(8) waits only t+1's loads, issued a full tile ago].
// Grid: round-4 row-major XCD chunks (the 47%-MfmaUtil config).

__global__ __launch_bounds__(512, 2) void gateup_kernel(
        const _Float16* __restrict__ Aptr, const _Float16* __restrict__ Bgp,
        const _Float16* __restrict__ Bup, const float* __restrict__ gsc,
        const float* __restrict__ usc, _Float16* __restrict__ H)
{
    constexpr int KDIM = HIDDEN;
    constexpr int NT = KDIM / 64;      // 64
    constexpr int NBN = INTER / 128;   // 112
    __shared__ _Float16 sA[2][256 * 64];
    __shared__ _Float16 sG[2][128 * 64];
    __shared__ _Float16 sU[2][128 * 64];

    const int tid  = threadIdx.x;
    const int lane = tid & 63;
    const int wid  = tid >> 6;
    const int wr   = wid >> 2;   // 0..1
    const int wc   = wid & 3;    // 0..3

    // round-4 mapping: contiguous swz chunk per XCD, bn fast
    const int nwg = gridDim.x;
    const int bid = blockIdx.x;
    const int swz = (bid & 7) * (nwg >> 3) + (bid >> 3);
    const int bm = swz / NBN;
    const int bn = swz % NBN;

    // staging addresses (T2: pre-swizzled global source slot)
    const int srow  = tid >> 3;                  // 0..63
    const int sslot = (tid & 7) ^ (srow & 7);
    const _Float16* gA = Aptr + ((long)bm * 256 + srow) * KDIM + sslot * 8;
    const _Float16* gG = Bgp + ((long)bn * 128 + srow) * KDIM + sslot * 8;
    const _Float16* gU = Bup + ((long)bn * 128 + srow) * KDIM + sslot * 8;

    auto stageAll = [&](int t) {   // full t-tile -> buf[t&1]: 8 loads/thread
        const int b = t & 1;
        _Float16* dA = &sA[b][tid * 8];
        _Float16* dG = &sG[b][tid * 8];
        _Float16* dU = &sU[b][tid * 8];
        const _Float16* sa = gA + (long)t * 64;
        const _Float16* sg = gG + (long)t * 64;
        const _Float16* su = gU + (long)t * 64;
#pragma unroll
        for (int p = 0; p < 4; ++p)
            __builtin_amdgcn_global_load_lds(AS1C(sa + (long)p * 64 * KDIM), AS3(dA + p * 4096), 16, 0, 0);
#pragma unroll
        for (int p = 0; p < 2; ++p) {
            __builtin_amdgcn_global_load_lds(AS1C(sg + (long)p * 64 * KDIM), AS3(dG + p * 4096), 16, 0, 0);
            __builtin_amdgcn_global_load_lds(AS1C(su + (long)p * 64 * KDIM), AS3(dU + p * 4096), 16, 0, 0);
        }
    };

    // ds_read fragment offsets (elements); row&7 == lane&7 for all frags
    const int arow = wr * 128 + (lane & 15);
    const int brow = wc * 32  + (lane & 15);
    const int sl0 = ((lane >> 4) ^ (lane & 7)) * 8;
    const int sl1 = ((4 + (lane >> 4)) ^ (lane & 7)) * 8;
    const int aof0 = arow * 64 + sl0, aof1 = arow * 64 + sl1;
    const int bof0 = brow * 64 + sl0, bof1 = brow * 64 + sl1;

    floatx4 ag[8][2] = {};
    floatx4 au[8][2] = {};
    half8 a[8][2], bg[2][2], bu[2][2];

    // prologue: depth-2
    stageAll(0);
    stageAll(1);
    WAIT_VM8();           // tile0 landed; tile1's 8 in flight
    SBAR();

    for (int t = 0; t < NT; ++t) {
        const _Float16* A = &sA[t & 1][0];
        const _Float16* G = &sG[t & 1][0];
        const _Float16* U = &sU[t & 1][0];

        // ---- P0: ds A0-3 + G; MFMA g m0-3 ----
#pragma unroll
        for (int m = 0; m < 4; ++m) {
            a[m][0] = *(const half8*)(A + aof0 + m * 1024);
            a[m][1] = *(const half8*)(A + aof1 + m * 1024);
        }
#pragma unroll
        for (int n = 0; n < 2; ++n) {
            bg[n][0] = *(const half8*)(G + bof0 + n * 1024);
            bg[n][1] = *(const half8*)(G + bof1 + n * 1024);
        }
        SBAR();
        PRIO(1);
#pragma unroll
        for (int m = 0; m < 4; ++m)
#pragma unroll
            for (int n = 0; n < 2; ++n) {
                ag[m][n] = MFMA16(a[m][0], bg[n][0], ag[m][n]);
                ag[m][n] = MFMA16(a[m][1], bg[n][1], ag[m][n]);
            }
        PRIO(0);
        SBAR();

        // ---- P1: ds A4-7; MFMA g m4-7 ----
#pragma unroll
        for (int m = 4; m < 8; ++m) {
            a[m][0] = *(const half8*)(A + aof0 + m * 1024);
            a[m][1] = *(const half8*)(A + aof1 + m * 1024);
        }
        SBAR();
        PRIO(1);
#pragma unroll
        for (int m = 4; m < 8; ++m)
#pragma unroll
            for (int n = 0; n < 2; ++n) {
                ag[m][n] = MFMA16(a[m][0], bg[n][0], ag[m][n]);
                ag[m][n] = MFMA16(a[m][1], bg[n][1], ag[m][n]);
            }
        PRIO(0);
        SBAR();

        // ---- P2: ds U; MFMA u m0-3 ----
#pragma unroll
        for (int n = 0; n < 2; ++n) {
            bu[n][0] = *(const half8*)(U + bof0 + n * 1024);
            bu[n][1] = *(const half8*)(U + bof1 + n * 1024);
        }
        SBAR();
        PRIO(1);
#pragma unroll
        for (int m = 0; m < 4; ++m)
#pragma unroll
            for (int n = 0; n < 2; ++n) {
                au[m][n] = MFMA16(a[m][0], bu[n][0], au[m][n]);
                au[m][n] = MFMA16(a[m][1], bu[n][1], au[m][n]);
            }
        PRIO(0);
        SBAR();

        // ---- P3: issue t+2 staging (cur buf fully read); MFMA u m4-7 ----
        if (t + 2 < NT) stageAll(t + 2);
        PRIO(1);
#pragma unroll
        for (int m = 4; m < 8; ++m)
#pragma unroll
            for (int n = 0; n < 2; ++n) {
                au[m][n] = MFMA16(a[m][0], bu[n][0], au[m][n]);
                au[m][n] = MFMA16(a[m][1], bu[n][1], au[m][n]);
            }
        PRIO(0);
        if (t + 2 < NT) { WAIT_VM8(); }   // waits only t+1's loads (a full tile old)
        else            { WAIT_VM0(); }
        SBAR();
    }

    // ---- epilogue: h = silu(g*gs) * (u*us), fp16 ----
    const int orow = bm * 256 + wr * 128 + ((lane >> 4) * 4);
    const int ocol = bn * 128 + wc * 32 + (lane & 15);
#pragma unroll
    for (int n = 0; n < 2; ++n) {
        const int col = ocol + n * 16;
        const float gs = gsc[col];
        const float us = usc[col];
#pragma unroll
        for (int m = 0; m < 8; ++m) {
            const int row = orow + m * 16;
#pragma unroll
            for (int q = 0; q < 4; ++q) {
                const float g = ag[m][n][q] * gs;
                const float u = au[m][n][q] * us;
                H[(long)(row + q) * INTER + col] = (_Float16)(g / (1.0f + __expf(-g)) * u);
            }
        }
    }
}

// ---------------- down GEMM (4-phase 256x256, depth-2 prefetch) ----------------

__global__ __launch_bounds__(512, 2) void down_kernel(
        const _Float16* __restrict__ Aptr, const _Float16* __restrict__ Bptr,
        const float* __restrict__ dsc, float* __restrict__ out)
{
    constexpr int KDIM = INTER;
    constexpr int NT = KDIM / 64;     // 224
    constexpr int NBN = HIDDEN / 256; // 16
    __shared__ _Float16 sA[2][256 * 64];
    __shared__ _Float16 sB[2][256 * 64];

    const int tid  = threadIdx.x;
    const int lane = tid & 63;
    const int wid  = tid >> 6;
    const int wr   = wid >> 2;
    const int wc   = wid & 3;

    const int nwg = gridDim.x;
    const int bid = blockIdx.x;
    const int swz = (bid & 7) * (nwg >> 3) + (bid >> 3);
    const int bm = swz / NBN;
    const int bn = swz % NBN;

    const int srow  = tid >> 3;
    const int sslot = (tid & 7) ^ (srow & 7);
    const _Float16* gA = Aptr + ((long)bm * 256 + srow) * KDIM + sslot * 8;
    const _Float16* gB = Bptr + ((long)bn * 256 + srow) * KDIM + sslot * 8;

    auto stageAll = [&](int t) {   // 8 loads/thread
        const int b = t & 1;
        _Float16* dA = &sA[b][tid * 8];
        _Float16* dB = &sB[b][tid * 8];
        const _Float16* sa = gA + (long)t * 64;
        const _Float16* sb = gB + (long)t * 64;
#pragma unroll
        for (int p = 0; p < 4; ++p) {
            __builtin_amdgcn_global_load_lds(AS1C(sa + (long)p * 64 * KDIM), AS3(dA + p * 4096), 16, 0, 0);
            __builtin_amdgcn_global_load_lds(AS1C(sb + (long)p * 64 * KDIM), AS3(dB + p * 4096), 16, 0, 0);
        }
    };

    const int arow = wr * 128 + (lane & 15);
    const int brow = wc * 64  + (lane & 15);
    const int sl0 = ((lane >> 4) ^ (lane & 7)) * 8;
    const int sl1 = ((4 + (lane >> 4)) ^ (lane & 7)) * 8;
    const int aof0 = arow * 64 + sl0, aof1 = arow * 64 + sl1;
    const int bof0 = brow * 64 + sl0, bof1 = brow * 64 + sl1;

    floatx4 acc[8][4] = {};
    half8 a[8][2], b[4][2];

    stageAll(0);
    stageAll(1);
    WAIT_VM8();
    SBAR();

    for (int t = 0; t < NT; ++t) {
        const _Float16* A = &sA[t & 1][0];
        const _Float16* B = &sB[t & 1][0];

        // ---- P0: ds A0-3 + B0-1; MFMA m0-3 x n0-1 ----
#pragma unroll
        for (int m = 0; m < 4; ++m) {
            a[m][0] = *(const half8*)(A + aof0 + m * 1024);
            a[m][1] = *(const half8*)(A + aof1 + m * 1024);
        }
#pragma unroll
        for (int n = 0; n < 2; ++n) {
            b[n][0] = *(const half8*)(B + bof0 + n * 1024);
            b[n][1] = *(const half8*)(B + bof1 + n * 1024);
        }
        SBAR();
        PRIO(1);
#pragma unroll
        for (int m = 0; m < 4; ++m)
#pragma unroll
            for (int n = 0; n < 2; ++n) {
                acc[m][n] = MFMA16(a[m][0], b[n][0], acc[m][n]);
                acc[m][n] = MFMA16(a[m][1], b[n][1], acc[m][n]);
            }
        PRIO(0);
        SBAR();

        // ---- P1: ds B2-3; MFMA m0-3 x n2-3 ----
#pragma unroll
        for (int n = 2; n < 4; ++n) {
            b[n][0] = *(const half8*)(B + bof0 + n * 1024);
            b[n][1] = *(const half8*)(B + bof1 + n * 1024);
        }
        SBAR();
        PRIO(1);
#pragma unroll
        for (int m = 0; m < 4; ++m)
#pragma unroll
            for (int n = 2; n < 4; ++n) {
                acc[m][n] = MFMA16(a[m][0], b[n][0], acc[m][n]);
                acc[m][n] = MFMA16(a[m][1], b[n][1], acc[m][n]);
            }
        PRIO(0);
        SBAR();

        // ---- P2: ds A4-7; MFMA m4-7 x n2-3 ----
#pragma unroll
        for (int m = 4; m < 8; ++m) {
            a[m][0] = *(const half8*)(A + aof0 + m * 1024);
            a[m][1] = *(const half8*)(A + aof1 + m * 1024);
        }
        SBAR();
        PRIO(1);
#pragma unroll
        for (int m = 4; m < 8; ++m)
#pragma unroll
            for (int n = 2; n < 4; ++n) {
                acc[m][n] = MFMA16(a[m][0], b[n][0], acc[m][n]);
                acc[m][n] = MFMA16(a[m][1], b[n][1], acc[m][n]);
            }
        PRIO(0);
        SBAR();

        // ---- P3: issue t+2 staging; MFMA m4-7 x n0-1 ----
        if (t + 2 < NT) stageAll(t + 2);
        PRIO(1);
#pragma unroll
        for (int m = 4; m < 8; ++m)
#pragma unroll
            for (int n = 0; n < 2; ++n) {
                acc[m][n] = MFMA16(a[m][0], b[n][0], acc[m][n]);
                acc[m][n] = MFMA16(a[m][1], b[n][1], acc[m][n]);
            }
        PRIO(0);
        if (t + 2 < NT) { WAIT_VM8(); }
        else            { WAIT_VM0(); }
        SBAR();
    }

    const int orow = bm * 256 + wr * 128 + ((lane >> 4) * 4);
    const int ocol = bn * 256 + wc * 64 + (lane & 15);
#pragma unroll
    for (int n = 0; n < 4; ++n) {
        const int col = ocol + n * 16;
        const float sc = dsc[col];
#pragma unroll
        for (int m = 0; m < 8; ++m) {
            const int row = orow + m * 16;
#pragma unroll
            for (int q = 0; q < 4; ++q)
                out[(long)(row + q) * HIDDEN + col] = acc[m][n][q] * sc;
        }
    }
}

// ---------------- launch ----------------

extern "C" void kernel_launch(void* const* d_in, const int* in_sizes, int n_in,
                              void* d_out, int out_size, void* d_ws, size_t ws_size,
                              hipStream_t stream) {
    const float* x   = (const float*)d_in[0];
    const int*   gw  = (const int*)d_in[1];
    const float* gsc = (const float*)d_in[2];
    const int*   uw  = (const int*)d_in[3];
    const float* usc = (const float*)d_in[4];
    const int*   dw  = (const int*)d_in[5];
    const float* dsc = (const float*)d_in[6];
    float* out = (float*)d_out;

    char* ws = (char*)d_ws;
    _Float16* x16  = (_Float16*)(ws);                    //  64 MiB
    _Float16* wg16 = (_Float16*)(ws + 67108864ll);       // 112 MiB
    _Float16* wu16 = (_Float16*)(ws + 184549376ll);      // 112 MiB
    _Float16* wd16 = (_Float16*)(ws + 301989888ll);      // 112 MiB
    _Float16* h16  = (_Float16*)(ws + 419430400ll);      // 224 MiB

    cvt_x_kernel<<<4096, 256, 0, stream>>>(x,  x16,  (long)NTOK * HIDDEN);
    cvt_w_kernel<<<4096, 256, 0, stream>>>(gw, wg16, (long)INTER * HIDDEN);
    cvt_w_kernel<<<4096, 256, 0, stream>>>(uw, wu16, (long)INTER * HIDDEN);
    cvt_w_kernel<<<4096, 256, 0, stream>>>(dw, wd16, (long)HIDDEN * INTER);

    // fused gate+up+SwiGLU: [8192 x 14336], h fp16
    gateup_kernel<<<(NTOK / 256) * (INTER / 128), 512, 0, stream>>>(
        x16, wg16, wu16, gsc, usc, h16);
    // down: [8192 x 4096] = H * Wd^T, fp32 out
    down_kernel<<<(NTOK / 256) * (HIDDEN / 256), 512, 0, stream>>>(
        h16, wd16, dsc, out);
}

// Round 7
// 3371.484 us; speedup vs baseline: 1.2027x; 1.0016x over previous
//
#include <hip/hip_runtime.h>

#define HIDDEN 4096
#define INTER 14336
#define NTOK 8192   // B*S = 4*2048

typedef _Float16 half8 __attribute__((ext_vector_type(8)));
typedef float floatx4 __attribute__((ext_vector_type(4)));

#define AS1C(p) ((const __attribute__((address_space(1))) void*)(p))
#define AS3(p)  ((__attribute__((address_space(3))) void*)(p))
#define SBAR()  __builtin_amdgcn_s_barrier()
#define SCHED0() __builtin_amdgcn_sched_barrier(0)
#define WAIT_VM0() asm volatile("s_waitcnt vmcnt(0)" ::: "memory")
#define WAIT_VM8() asm volatile("s_waitcnt vmcnt(8)" ::: "memory")
#define PRIO(x) __builtin_amdgcn_s_setprio(x)
#define MFMA16(A,B,C) __builtin_amdgcn_mfma_f32_16x16x32_f16(A,B,C,0,0,0)

// ---------------- conversion kernels ----------------

__global__ void cvt_w_kernel(const int* __restrict__ src, _Float16* __restrict__ dst, long n) {
    long i0 = ((long)blockIdx.x * blockDim.x + threadIdx.x) * 8;
    long stride = (long)gridDim.x * blockDim.x * 8;
    for (long i = i0; i < n; i += stride) {
        int4 a = *(const int4*)(src + i);
        int4 b = *(const int4*)(src + i + 4);
        half8 h;
        h[0] = (_Float16)a.x; h[1] = (_Float16)a.y; h[2] = (_Float16)a.z; h[3] = (_Float16)a.w;
        h[4] = (_Float16)b.x; h[5] = (_Float16)b.y; h[6] = (_Float16)b.z; h[7] = (_Float16)b.w;
        *(half8*)(dst + i) = h;
    }
}

__global__ void cvt_x_kernel(const float* __restrict__ src, _Float16* __restrict__ dst, long n) {
    long i0 = ((long)blockIdx.x * blockDim.x + threadIdx.x) * 8;
    long stride = (long)gridDim.x * blockDim.x * 8;
    for (long i = i0; i < n; i += stride) {
        float4 a = *(const float4*)(src + i);
        float4 b = *(const float4*)(src + i + 4);
        half8 h;
        h[0] = (_Float16)a.x; h[1] = (_Float16)a.y; h[2] = (_Float16)a.z; h[3] = (_Float16)a.w;
        h[4] = (_Float16)b.x; h[5] = (_Float16)b.y; h[6] = (_Float16)b.z; h[7] = (_Float16)b.w;
        *(half8*)(dst + i) = h;
    }
}

// ---------------- fused gate+up (4-phase, fragment-lookahead pipeline) ----------------
// BM=256, BN=128, BK=64, 512 thr (8 waves 2Mx4N). LDS 128KB: 2buf x (A32K+G16K+U16K).
// Frag banks: aLo (A m0-3), aHi (A m4-7), bg, bu. Reads are ONE PHASE AHEAD of use,
// so MFMA overlaps in-flight ds_reads via compiler's counted lgkmcnt:
//   X0: read aHi      | MFMA (aLo,bg) -> ag[0-3]   [aLo,bg loaded at X3 of t-1]
//   X1: read bu       | MFMA (aHi,bg) -> ag[4-7]
//   X2: stage t+2     | MFMA (aLo,bu) -> au[0-3]; vmcnt(8) [t+1 landed, t+2 in flight]
//   X3: read aLo',bg' | MFMA (aHi,bu) -> au[4-7]   [from t+1 buffer]
// One counted vmcnt(8)/tile; 8 loads always in flight; stage at X2 is 4 phases
// before its drain. Grid: R4 row-major XCD chunks (bn fast).

__global__ __launch_bounds__(512, 2) void gateup_kernel(
        const _Float16* __restrict__ Aptr, const _Float16* __restrict__ Bgp,
        const _Float16* __restrict__ Bup, const float* __restrict__ gsc,
        const float* __restrict__ usc, _Float16* __restrict__ H)
{
    constexpr int KDIM = HIDDEN;
    constexpr int NT = KDIM / 64;      // 64
    constexpr int NBN = INTER / 128;   // 112
    __shared__ _Float16 sA[2][256 * 64];
    __shared__ _Float16 sG[2][128 * 64];
    __shared__ _Float16 sU[2][128 * 64];

    const int tid  = threadIdx.x;
    const int lane = tid & 63;
    const int wid  = tid >> 6;
    const int wr   = wid >> 2;   // 0..1
    const int wc   = wid & 3;    // 0..3

    const int nwg = gridDim.x;
    const int bid = blockIdx.x;
    const int swz = (bid & 7) * (nwg >> 3) + (bid >> 3);
    const int bm = swz / NBN;
    const int bn = swz % NBN;

    const int srow  = tid >> 3;                  // 0..63
    const int sslot = (tid & 7) ^ (srow & 7);    // T2 pre-swizzled source slot
    const _Float16* gA = Aptr + ((long)bm * 256 + srow) * KDIM + sslot * 8;
    const _Float16* gG = Bgp + ((long)bn * 128 + srow) * KDIM + sslot * 8;
    const _Float16* gU = Bup + ((long)bn * 128 + srow) * KDIM + sslot * 8;

    auto stageAll = [&](int t) {   // full t-tile -> buf[t&1]: 8 loads/thread
        const int b = t & 1;
        _Float16* dA = &sA[b][tid * 8];
        _Float16* dG = &sG[b][tid * 8];
        _Float16* dU = &sU[b][tid * 8];
        const _Float16* sa = gA + (long)t * 64;
        const _Float16* sg = gG + (long)t * 64;
        const _Float16* su = gU + (long)t * 64;
#pragma unroll
        for (int p = 0; p < 4; ++p)
            __builtin_amdgcn_global_load_lds(AS1C(sa + (long)p * 64 * KDIM), AS3(dA + p * 4096), 16, 0, 0);
#pragma unroll
        for (int p = 0; p < 2; ++p) {
            __builtin_amdgcn_global_load_lds(AS1C(sg + (long)p * 64 * KDIM), AS3(dG + p * 4096), 16, 0, 0);
            __builtin_amdgcn_global_load_lds(AS1C(su + (long)p * 64 * KDIM), AS3(dU + p * 4096), 16, 0, 0);
        }
    };

    const int arow = wr * 128 + (lane & 15);
    const int brow = wc * 32  + (lane & 15);
    const int sl0 = ((lane >> 4) ^ (lane & 7)) * 8;
    const int sl1 = ((4 + (lane >> 4)) ^ (lane & 7)) * 8;
    const int aof0 = arow * 64 + sl0, aof1 = arow * 64 + sl1;
    const int bof0 = brow * 64 + sl0, bof1 = brow * 64 + sl1;

    floatx4 ag[8][2] = {};
    floatx4 au[8][2] = {};
    half8 aLo[4][2], aHi[4][2], bg[2][2], bu[2][2];

    // ---- prologue: stage t0,t1; wait t0; preload aLo(0), bg(0) ----
    stageAll(0);
    stageAll(1);
    WAIT_VM8();
    SBAR();
    {
        const _Float16* A = &sA[0][0];
        const _Float16* G = &sG[0][0];
#pragma unroll
        for (int m = 0; m < 4; ++m) {
            aLo[m][0] = *(const half8*)(A + aof0 + m * 1024);
            aLo[m][1] = *(const half8*)(A + aof1 + m * 1024);
        }
#pragma unroll
        for (int n = 0; n < 2; ++n) {
            bg[n][0] = *(const half8*)(G + bof0 + n * 1024);
            bg[n][1] = *(const half8*)(G + bof1 + n * 1024);
        }
    }

    for (int t = 0; t < NT; ++t) {
        const _Float16* A  = &sA[t & 1][0];
        const _Float16* U  = &sU[t & 1][0];
        const _Float16* An = &sA[(t + 1) & 1][0];
        const _Float16* Gn = &sG[(t + 1) & 1][0];

        // ---- X0: read aHi(t) | MFMA (aLo,bg) -> ag[0-3] ----
#pragma unroll
        for (int m = 0; m < 4; ++m) {
            aHi[m][0] = *(const half8*)(A + aof0 + (4 + m) * 1024);
            aHi[m][1] = *(const half8*)(A + aof1 + (4 + m) * 1024);
        }
        SCHED0();
        SBAR();
        PRIO(1);
#pragma unroll
        for (int m = 0; m < 4; ++m)
#pragma unroll
            for (int n = 0; n < 2; ++n) {
                ag[m][n] = MFMA16(aLo[m][0], bg[n][0], ag[m][n]);
                ag[m][n] = MFMA16(aLo[m][1], bg[n][1], ag[m][n]);
            }
        PRIO(0);
        SBAR();

        // ---- X1: read bu(t) | MFMA (aHi,bg) -> ag[4-7] ----
#pragma unroll
        for (int n = 0; n < 2; ++n) {
            bu[n][0] = *(const half8*)(U + bof0 + n * 1024);
            bu[n][1] = *(const half8*)(U + bof1 + n * 1024);
        }
        SCHED0();
        SBAR();
        PRIO(1);
#pragma unroll
        for (int m = 0; m < 4; ++m)
#pragma unroll
            for (int n = 0; n < 2; ++n) {
                ag[4 + m][n] = MFMA16(aHi[m][0], bg[n][0], ag[4 + m][n]);
                ag[4 + m][n] = MFMA16(aHi[m][1], bg[n][1], ag[4 + m][n]);
            }
        PRIO(0);
        SBAR();

        // ---- X2: stage t+2 into cur buf | MFMA (aLo,bu) -> au[0-3]; counted wait ----
        if (t + 2 < NT) stageAll(t + 2);
        SBAR();
        PRIO(1);
#pragma unroll
        for (int m = 0; m < 4; ++m)
#pragma unroll
            for (int n = 0; n < 2; ++n) {
                au[m][n] = MFMA16(aLo[m][0], bu[n][0], au[m][n]);
                au[m][n] = MFMA16(aLo[m][1], bu[n][1], au[m][n]);
            }
        PRIO(0);
        if (t + 2 < NT)      { WAIT_VM8(); }   // t+1 landed, t+2 stays in flight
        else if (t + 1 < NT) { WAIT_VM0(); }
        SBAR();

        // ---- X3: read aLo(t+1), bg(t+1) | MFMA (aHi,bu) -> au[4-7] ----
        if (t + 1 < NT) {
#pragma unroll
            for (int m = 0; m < 4; ++m) {
                aLo[m][0] = *(const half8*)(An + aof0 + m * 1024);
                aLo[m][1] = *(const half8*)(An + aof1 + m * 1024);
            }
#pragma unroll
            for (int n = 0; n < 2; ++n) {
                bg[n][0] = *(const half8*)(Gn + bof0 + n * 1024);
                bg[n][1] = *(const half8*)(Gn + bof1 + n * 1024);
            }
        }
        SCHED0();
        SBAR();
        PRIO(1);
#pragma unroll
        for (int m = 0; m < 4; ++m)
#pragma unroll
            for (int n = 0; n < 2; ++n) {
                au[4 + m][n] = MFMA16(aHi[m][0], bu[n][0], au[4 + m][n]);
                au[4 + m][n] = MFMA16(aHi[m][1], bu[n][1], au[4 + m][n]);
            }
        PRIO(0);
        SBAR();
    }

    // ---- epilogue: h = silu(g*gs) * (u*us), fp16 ----
    const int orow = bm * 256 + wr * 128 + ((lane >> 4) * 4);
    const int ocol = bn * 128 + wc * 32 + (lane & 15);
#pragma unroll
    for (int n = 0; n < 2; ++n) {
        const int col = ocol + n * 16;
        const float gs = gsc[col];
        const float us = usc[col];
#pragma unroll
        for (int m = 0; m < 8; ++m) {
            const int row = orow + m * 16;
#pragma unroll
            for (int q = 0; q < 4; ++q) {
                const float g = ag[m][n][q] * gs;
                const float u = au[m][n][q] * us;
                H[(long)(row + q) * INTER + col] = (_Float16)(g / (1.0f + __expf(-g)) * u);
            }
        }
    }
}

// ---------------- down GEMM (4-phase 256x256, fragment-lookahead pipeline) ----------------
//   X0: read b23      | MFMA (aLo,b01) -> acc[0-3][0-1]
//   X1: read aHi      | MFMA (aLo,b23) -> acc[0-3][2-3]
//   X2: stage t+2     | MFMA (aHi,b01) -> acc[4-7][0-1]; vmcnt(8)
//   X3: read aLo',b01'| MFMA (aHi,b23) -> acc[4-7][2-3]

__global__ __launch_bounds__(512, 2) void down_kernel(
        const _Float16* __restrict__ Aptr, const _Float16* __restrict__ Bptr,
        const float* __restrict__ dsc, float* __restrict__ out)
{
    constexpr int KDIM = INTER;
    constexpr int NT = KDIM / 64;     // 224
    constexpr int NBN = HIDDEN / 256; // 16
    __shared__ _Float16 sA[2][256 * 64];
    __shared__ _Float16 sB[2][256 * 64];

    const int tid  = threadIdx.x;
    const int lane = tid & 63;
    const int wid  = tid >> 6;
    const int wr   = wid >> 2;
    const int wc   = wid & 3;

    const int nwg = gridDim.x;
    const int bid = blockIdx.x;
    const int swz = (bid & 7) * (nwg >> 3) + (bid >> 3);
    const int bm = swz / NBN;
    const int bn = swz % NBN;

    const int srow  = tid >> 3;
    const int sslot = (tid & 7) ^ (srow & 7);
    const _Float16* gA = Aptr + ((long)bm * 256 + srow) * KDIM + sslot * 8;
    const _Float16* gB = Bptr + ((long)bn * 256 + srow) * KDIM + sslot * 8;

    auto stageAll = [&](int t) {   // 8 loads/thread
        const int b = t & 1;
        _Float16* dA = &sA[b][tid * 8];
        _Float16* dB = &sB[b][tid * 8];
        const _Float16* sa = gA + (long)t * 64;
        const _Float16* sb = gB + (long)t * 64;
#pragma unroll
        for (int p = 0; p < 4; ++p) {
            __builtin_amdgcn_global_load_lds(AS1C(sa + (long)p * 64 * KDIM), AS3(dA + p * 4096), 16, 0, 0);
            __builtin_amdgcn_global_load_lds(AS1C(sb + (long)p * 64 * KDIM), AS3(dB + p * 4096), 16, 0, 0);
        }
    };

    const int arow = wr * 128 + (lane & 15);
    const int brow = wc * 64  + (lane & 15);
    const int sl0 = ((lane >> 4) ^ (lane & 7)) * 8;
    const int sl1 = ((4 + (lane >> 4)) ^ (lane & 7)) * 8;
    const int aof0 = arow * 64 + sl0, aof1 = arow * 64 + sl1;
    const int bof0 = brow * 64 + sl0, bof1 = brow * 64 + sl1;

    floatx4 acc[8][4] = {};
    half8 aLo[4][2], aHi[4][2], b01[2][2], b23[2][2];

    stageAll(0);
    stageAll(1);
    WAIT_VM8();
    SBAR();
    {
        const _Float16* A = &sA[0][0];
        const _Float16* B = &sB[0][0];
#pragma unroll
        for (int m = 0; m < 4; ++m) {
            aLo[m][0] = *(const half8*)(A + aof0 + m * 1024);
            aLo[m][1] = *(const half8*)(A + aof1 + m * 1024);
        }
#pragma unroll
        for (int n = 0; n < 2; ++n) {
            b01[n][0] = *(const half8*)(B + bof0 + n * 1024);
            b01[n][1] = *(const half8*)(B + bof1 + n * 1024);
        }
    }

    for (int t = 0; t < NT; ++t) {
        const _Float16* A  = &sA[t & 1][0];
        const _Float16* B  = &sB[t & 1][0];
        const _Float16* An = &sA[(t + 1) & 1][0];
        const _Float16* Bn = &sB[(t + 1) & 1][0];

        // ---- X0: read b23(t) | MFMA (aLo,b01) ----
#pragma unroll
        for (int n = 0; n < 2; ++n) {
            b23[n][0] = *(const half8*)(B + bof0 + (2 + n) * 1024);
            b23[n][1] = *(const half8*)(B + bof1 + (2 + n) * 1024);
        }
        SCHED0();
        SBAR();
        PRIO(1);
#pragma unroll
        for (int m = 0; m < 4; ++m)
#pragma unroll
            for (int n = 0; n < 2; ++n) {
                acc[m][n] = MFMA16(aLo[m][0], b01[n][0], acc[m][n]);
                acc[m][n] = MFMA16(aLo[m][1], b01[n][1], acc[m][n]);
            }
        PRIO(0);
        SBAR();

        // ---- X1: read aHi(t) | MFMA (aLo,b23) ----
#pragma unroll
        for (int m = 0; m < 4; ++m) {
            aHi[m][0] = *(const half8*)(A + aof0 + (4 + m) * 1024);
            aHi[m][1] = *(const half8*)(A + aof1 + (4 + m) * 1024);
        }
        SCHED0();
        SBAR();
        PRIO(1);
#pragma unroll
        for (int m = 0; m < 4; ++m)
#pragma unroll
            for (int n = 0; n < 2; ++n) {
                acc[m][2 + n] = MFMA16(aLo[m][0], b23[n][0], acc[m][2 + n]);
                acc[m][2 + n] = MFMA16(aLo[m][1], b23[n][1], acc[m][2 + n]);
            }
        PRIO(0);
        SBAR();

        // ---- X2: stage t+2 | MFMA (aHi,b01); counted wait ----
        if (t + 2 < NT) stageAll(t + 2);
        SBAR();
        PRIO(1);
#pragma unroll
        for (int m = 0; m < 4; ++m)
#pragma unroll
            for (int n = 0; n < 2; ++n) {
                acc[4 + m][n] = MFMA16(aHi[m][0], b01[n][0], acc[4 + m][n]);
                acc[4 + m][n] = MFMA16(aHi[m][1], b01[n][1], acc[4 + m][n]);
            }
        PRIO(0);
        if (t + 2 < NT)      { WAIT_VM8(); }
        else if (t + 1 < NT) { WAIT_VM0(); }
        SBAR();

        // ---- X3: read aLo(t+1), b01(t+1) | MFMA (aHi,b23) ----
        if (t + 1 < NT) {
#pragma unroll
            for (int m = 0; m < 4; ++m) {
                aLo[m][0] = *(const half8*)(An + aof0 + m * 1024);
                aLo[m][1] = *(const half8*)(An + aof1 + m * 1024);
            }
#pragma unroll
            for (int n = 0; n < 2; ++n) {
                b01[n][0] = *(const half8*)(Bn + bof0 + n * 1024);
                b01[n][1] = *(const half8*)(Bn + bof1 + n * 1024);
            }
        }
        SCHED0();
        SBAR();
        PRIO(1);
#pragma unroll
        for (int m = 0; m < 4; ++m)
#pragma unroll
            for (int n = 0; n < 2; ++n) {
                acc[4 + m][2 + n] = MFMA16(aHi[m][0], b23[n][0], acc[4 + m][2 + n]);
                acc[4 + m][2 + n] = MFMA16(aHi[m][1], b23[n][1], acc[4 + m][2 + n]);
            }
        PRIO(0);
        SBAR();
    }

    const int orow = bm * 256 + wr * 128 + ((lane >> 4) * 4);
    const int ocol = bn * 256 + wc * 64 + (lane & 15);
#pragma unroll
    for (int n = 0; n < 4; ++n) {
        const int col = ocol + n * 16;
        const float sc = dsc[col];
#pragma unroll
        for (int m = 0; m < 8; ++m) {
            const int row = orow + m * 16;
#pragma unroll
            for (int q = 0; q < 4; ++q)
                out[(long)(row + q) * HIDDEN + col] = acc[m][n][q] * sc;
        }
    }
}

// ---------------- launch ----------------

extern "C" void kernel_launch(void* const* d_in, const int* in_sizes, int n_in,
                              void* d_out, int out_size, void* d_ws, size_t ws_size,
                              hipStream_t stream) {
    const float* x   = (const float*)d_in[0];
    const int*   gw  = (const int*)d_in[1];
    const float* gsc = (const float*)d_in[2];
    const int*   uw  = (const int*)d_in[3];
    const float* usc = (const float*)d_in[4];
    const int*   dw  = (const int*)d_in[5];
    const float* dsc = (const float*)d_in[6];
    float* out = (float*)d_out;

    char* ws = (char*)d_ws;
    _Float16* x16  = (_Float16*)(ws);                    //  64 MiB
    _Float16* wg16 = (_Float16*)(ws + 67108864ll);       // 112 MiB
    _Float16* wu16 = (_Float16*)(ws + 184549376ll);      // 112 MiB
    _Float16* wd16 = (_Float16*)(ws + 301989888ll);      // 112 MiB
    _Float16* h16  = (_Float16*)(ws + 419430400ll);      // 224 MiB

    cvt_x_kernel<<<4096, 256, 0, stream>>>(x,  x16,  (long)NTOK * HIDDEN);
    cvt_w_kernel<<<4096, 256, 0, stream>>>(gw, wg16, (long)INTER * HIDDEN);
    cvt_w_kernel<<<4096, 256, 0, stream>>>(uw, wu16, (long)INTER * HIDDEN);
    cvt_w_kernel<<<4096, 256, 0, stream>>>(dw, wd16, (long)HIDDEN * INTER);

    // fused gate+up+SwiGLU: [8192 x 14336], h fp16
    gateup_kernel<<<(NTOK / 256) * (INTER / 128), 512, 0, stream>>>(
        x16, wg16, wu16, gsc, usc, h16);
    // down: [8192 x 4096] = H * Wd^T, fp32 out
    down_kernel<<<(NTOK / 256) * (HIDDEN / 256), 512, 0, stream>>>(
        h16, wd16, dsc, out);
}